// Round 1
// baseline (592.832 us; speedup 1.0000x reference)
//
#include <hip/hip_runtime.h>
#include <math.h>

#define DIM      32
#define N_EDGES  1600000
#define L0       0.1f

// one wave = 2 edges; lane = 32*half + d.  Lane d owns dimension d.
__global__ __launch_bounds__(256) void spring_edge_kernel(
    const float* __restrict__ x,
    const int*   __restrict__ edges,
    float*       __restrict__ out)   // out[0] = energy, out+1 = grad (N,DIM)
{
    const int tid    = threadIdx.x;
    const int lane   = tid & 63;
    const int d      = lane & 31;     // dimension index
    const int half   = lane >> 5;     // which of the wave's 2 edges
    const int waveId = (blockIdx.x * blockDim.x + tid) >> 6;
    const int nWaves = (gridDim.x * blockDim.x) >> 6;

    float* __restrict__ grad = out + 1;
    const float Jd = (d == 0) ? -1.0f : 1.0f;

    double energy = 0.0;

    for (int e0 = waveId * 2; e0 < N_EDGES; e0 += nWaves * 2) {
        const int  e      = e0 + half;
        const bool active = (e < N_EDGES);

        int   u = 0, v = 0;
        float xu = 0.0f, xv = 0.0f;
        if (active) {
            u  = edges[2 * e];
            v  = edges[2 * e + 1];
            xu = x[u * DIM + d];          // contiguous 128B row per half-wave
            xv = x[v * DIM + d];
        }

        // Minkowski inner product in f64: products of f32 are EXACT in f64,
        // so the reduction is order-independent to ~6e-14 — the clamp
        // decision below matches an f64 reference deterministically
        // (critical for self-edges where inner ~ -1 +- 1e-6).
        double p = (double)xu * (double)xv;
        if (d == 0) p = -p;
        #pragma unroll
        for (int off = 16; off; off >>= 1)
            p += __shfl_xor(p, off, 32);

        double inner = p;
        const double clampv = -1.0 - 1e-7;
        if (!(inner < clampv)) inner = clampv;      // min(inner, -1-1e-7)
        double zm1d = -inner - 1.0;                  // z-1 >= 1e-7, exact-ish

        // f32 tail computed from (z-1) to preserve precision near z=1:
        //   s    = sqrt(z^2-1) = sqrt((z-1)(z+1))
        //   dist = acosh(z)    = log1p((z-1) + s)
        float zm1    = (float)zm1d;
        float s      = sqrtf(zm1 * (zm1 + 2.0f));
        float dist   = log1pf(zm1 + s);
        float delta  = dist - L0;
        float factor = -delta / (s + 1e-9f);         // K = 1

        if (active) {
            atomicAdd(&grad[u * DIM + d], factor * xv * Jd);
            atomicAdd(&grad[v * DIM + d], factor * xu * Jd);
            if (d == 0)
                energy += 0.5 * (double)delta * (double)delta;
        }
    }

    // energy: wave reduce (only d==0 lanes hold nonzero) -> block -> 1 atomic
    #pragma unroll
    for (int off = 32; off; off >>= 1)
        energy += __shfl_xor(energy, off, 64);

    __shared__ double s_e[4];
    if (lane == 0) s_e[tid >> 6] = energy;
    __syncthreads();
    if (tid == 0) {
        double tot = s_e[0] + s_e[1] + s_e[2] + s_e[3];
        atomicAdd(&out[0], (float)tot);
    }
}

extern "C" void kernel_launch(void* const* d_in, const int* in_sizes, int n_in,
                              void* d_out, int out_size, void* d_ws, size_t ws_size,
                              hipStream_t stream) {
    const float* x     = (const float*)d_in[0];
    const int*   edges = (const int*)d_in[1];
    float*       out   = (float*)d_out;

    // harness poisons d_out with 0xAA every call — zero energy + grad
    hipMemsetAsync(out, 0, (size_t)out_size * sizeof(float), stream);

    // 4096 blocks x 4 waves = 16384 waves (2x oversubscription of 8192-wave
    // capacity), grid-stride over 1.6M edges, 2 edges per wave per iter.
    spring_edge_kernel<<<4096, 256, 0, stream>>>(x, edges, out);
}